// Round 9
// baseline (675.703 us; speedup 1.0000x reference)
//
#include <hip/hip_runtime.h>
#include <cmath>

#define LOG2E 1.44269504088896340736f
#define SWZ(x, pat) \
  __int_as_float(__builtin_amdgcn_ds_swizzle(__float_as_int(x), (pat)))

typedef __attribute__((ext_vector_type(8))) short s16x8;          // bf16 MFMA frag
typedef __attribute__((ext_vector_type(8))) unsigned short u16x8; // 16B copies
typedef __attribute__((ext_vector_type(4))) float f32x4;

static constexpr int N = 4096;
static constexpr int C = 64;

__device__ __forceinline__ unsigned short f2b(float f) {  // RNE fp32->bf16
  union { float f; unsigned int i; } c; c.f = f;
  return (unsigned short)((c.i + 0x7fffu + ((c.i >> 16) & 1u)) >> 16);
}
__device__ __forceinline__ s16x8 pack8s(const float* p, float sc) {
  float4 a = *(const float4*)p, b = *(const float4*)(p + 4);
  s16x8 r;
  r[0] = (short)f2b(a.x * sc); r[1] = (short)f2b(a.y * sc);
  r[2] = (short)f2b(a.z * sc); r[3] = (short)f2b(a.w * sc);
  r[4] = (short)f2b(b.x * sc); r[5] = (short)f2b(b.y * sc);
  r[6] = (short)f2b(b.z * sc); r[7] = (short)f2b(b.w * sc);
  return r;
}

// ---- prep (R7-verified, verbatim): 0..383 transpose K; 384..1919 cast V ---
__global__ void k_prep(const float* __restrict__ k0, const float* __restrict__ k1,
                       const float* __restrict__ k2, const float* __restrict__ v0,
                       const float* __restrict__ v1, const float* __restrict__ v2,
                       unsigned short* __restrict__ kt, unsigned short* __restrict__ vb) {
  int tid = threadIdx.x;
  if (blockIdx.x < 384) {
    int blk = blockIdx.x;          // slot*64 + jt
    int jt = blk & 63, slot = blk >> 6;
    int b = slot & 1, ks = slot >> 1;
    const float* k = (ks == 0 ? k0 : ks == 1 ? k1 : k2) + (size_t)b * C * N;
    __shared__ __align__(16) unsigned short t[64][72];
    int j0 = jt * 64;
    int d = tid >> 2, jq = (tid & 3) * 16;
#pragma unroll
    for (int q = 0; q < 4; q++) {
      float4 v = *(const float4*)(k + (size_t)d * N + j0 + jq + q * 4);
      t[jq + q * 4 + 0][d] = f2b(v.x);
      t[jq + q * 4 + 1][d] = f2b(v.y);
      t[jq + q * 4 + 2][d] = f2b(v.z);
      t[jq + q * 4 + 3][d] = f2b(v.w);
    }
    __syncthreads();
    unsigned short* o = kt + (size_t)slot * N * C + (size_t)j0 * C;
#pragma unroll
    for (int l = 0; l < 2; l++) {
      int i = tid + l * 256;
      int j = i >> 3, d8 = (i & 7) * 8;
      *(u16x8*)(o + j * 64 + d8) = *(const u16x8*)&t[j][d8];
    }
  } else {
    int id = blockIdx.x - 384;     // 1536 blocks: slot = id/256
    int slot = id >> 8, bi = id & 255;
    int b = slot & 1, qs = slot >> 1;
    const float* v = (qs == 0 ? v0 : qs == 1 ? v1 : v2) + (size_t)b * C * N;
    size_t idx = ((size_t)bi * 256 + tid) * 4;
    float4 f = *(const float4*)(v + idx);
    ushort4 u;
    u.x = f2b(f.x); u.y = f2b(f.y); u.z = f2b(f.z); u.w = f2b(f.w);
    *(ushort4*)(vb + (size_t)slot * C * N + idx) = u;
  }
}

// ---- main: single-wave flash attention (R7 addressing) --------------------
// grid 4608 = (b,qs,ks) x 64 q-tiles x 4 strips; 1 wave per 16 q-rows.
__global__ __launch_bounds__(64, 4) void k_flash(
    const float* __restrict__ q0, const float* __restrict__ q1,
    const float* __restrict__ q2, const unsigned short* __restrict__ KT,
    const unsigned short* __restrict__ Vb, const float* __restrict__ x0,
    const float* __restrict__ x1, const float* __restrict__ x2,
    const float* __restrict__ bias0, const float* __restrict__ bias1,
    const float* __restrict__ bias2, const float* __restrict__ w0,
    const float* __restrict__ w1, const float* __restrict__ w2,
    float* __restrict__ out) {
  __shared__ __align__(16) unsigned short pt[16][72];  // P strip [i][j] / O [i][c]

  int blk = blockIdx.x;
  int sub = blk & 3;
  int qt = (blk >> 2) & 63;
  int r3 = blk >> 8;                  // 0..17
  int b = r3 / 9, rem = r3 % 9, qs = rem / 3, ks = rem % 3;

  int lane = threadIdx.x & 63;
  int g = lane >> 4;                  // quad
  int ln = lane & 15;

  int i0 = qt * 64 + sub * 16;
  // Q A-fragments scaled by log2(e): A[m=ln][k=g*8+t]
  const float* qsrc = (qs == 0 ? q0 : qs == 1 ? q1 : q2);
  const float* qb = qsrc + (size_t)b * N * C + (size_t)(i0 + ln) * C;
  s16x8 qa0 = pack8s(qb + g * 8, LOG2E);
  s16x8 qa1 = pack8s(qb + 32 + g * 8, LOG2E);

  const unsigned short* ktg = KT + ((size_t)(ks * 2 + b)) * N * C;
  const unsigned short* vbg = Vb + ((size_t)(qs * 2 + b)) * C * N;
  const unsigned short* kl = ktg + (size_t)ln * 64 + g * 8;   // lane base (R7)
  const unsigned short* vl = vbg + (size_t)ln * N + g * 8;    // lane base (R7)

  f32x4 oacc[4];                      // O[row i=4g+r][col c=cc*16+ln]
#pragma unroll
  for (int cc = 0; cc < 4; cc++) oacc[cc] = (f32x4){0.f, 0.f, 0.f, 0.f};
  float l_r[4] = {0.f, 0.f, 0.f, 0.f};

  // K frag prologue (jt = 0)
  s16x8 ka0[4], ka1[4];
#pragma unroll
  for (int nc = 0; nc < 4; nc++) {
    ka0[nc] = *(const s16x8*)(kl + nc * 1024);
    ka1[nc] = *(const s16x8*)(kl + nc * 1024 + 32);
  }

  for (int jt = 0; jt < 64; jt++) {
    // V frags for this iteration (R7 addressing)
    s16x8 va0[4], va1[4];
#pragma unroll
    for (int cc = 0; cc < 4; cc++) {
      const unsigned short* vr = vl + (size_t)cc * 16 * N + jt * 64;
      va0[cc] = *(const s16x8*)(vr);
      va1[cc] = *(const s16x8*)(vr + 32);
    }
    // S strip: D[m=i][n=j] (log2 domain, Q pre-scaled)
    f32x4 s[4];
#pragma unroll
    for (int nc = 0; nc < 4; nc++) {
      f32x4 acc = (f32x4){0.f, 0.f, 0.f, 0.f};
      acc = __builtin_amdgcn_mfma_f32_16x16x32_bf16(qa0, ka0[nc], acc, 0, 0, 0);
      acc = __builtin_amdgcn_mfma_f32_16x16x32_bf16(qa1, ka1[nc], acc, 0, 0, 0);
      s[nc] = acc;
    }
    // prefetch K for jt+1 (tail overruns into Vb region: allocated, unused)
    const unsigned short* kn = kl + (size_t)(jt + 1) * 4096;
#pragma unroll
    for (int nc = 0; nc < 4; nc++) {
      ka0[nc] = *(const s16x8*)(kn + nc * 1024);
      ka1[nc] = *(const s16x8*)(kn + nc * 1024 + 32);
    }
    // no-max softmax: p = 2^s; l accumulated per-lane (deferred reduce)
#pragma unroll
    for (int nc = 0; nc < 4; nc++)
#pragma unroll
      for (int r = 0; r < 4; r++) {
        float p;
        asm("v_exp_f32 %0, %1" : "=v"(p) : "v"(s[nc][r]));
        l_r[r] += p;
        pt[4 * g + r][nc * 16 + ln] = f2b(p);
      }
    asm volatile("s_waitcnt lgkmcnt(0)" ::: "memory");  // cross-lane LDS RAW
    // PV: O[i][c] += P(A)[i][j] * V(B)[j][c]
    s16x8 pa0 = *(const s16x8*)&pt[ln][g * 8];
    s16x8 pa1 = *(const s16x8*)&pt[ln][32 + g * 8];
#pragma unroll
    for (int cc = 0; cc < 4; cc++) {
      oacc[cc] = __builtin_amdgcn_mfma_f32_16x16x32_bf16(pa0, va0[cc], oacc[cc], 0, 0, 0);
      oacc[cc] = __builtin_amdgcn_mfma_f32_16x16x32_bf16(pa1, va1[cc], oacc[cc], 0, 0, 0);
    }
    asm volatile("s_waitcnt lgkmcnt(0)" ::: "memory");  // pt reads before overwrite
  }
  // deferred l-reduction across the 16 lanes of each quad (xor 1,2,4,8)
#pragma unroll
  for (int r = 0; r < 4; r++) {
    l_r[r] += SWZ(l_r[r], 0x041F);
    l_r[r] += SWZ(l_r[r], 0x081F);
    l_r[r] += SWZ(l_r[r], 0x101F);
    l_r[r] += SWZ(l_r[r], 0x201F);
  }
  // ---- epilogue: OUT[o][i] = sum_c w[o][c]*(O[i][c]/l[i]) + bias[o] + x[o][i]
#pragma unroll
  for (int r = 0; r < 4; r++) {
    float linv = 1.0f / l_r[r];
#pragma unroll
    for (int cc = 0; cc < 4; cc++)
      pt[4 * g + r][cc * 16 + ln] = f2b(oacc[cc][r] * linv);  // [i][c]
  }
  asm volatile("s_waitcnt lgkmcnt(0)" ::: "memory");
  s16x8 ob0 = *(const s16x8*)&pt[ln][g * 8];   // B[k=c][n=i-local]
  s16x8 ob1 = *(const s16x8*)&pt[ln][32 + g * 8];
  const float* wsel = (qs == 0 ? w0 : qs == 1 ? w1 : w2);
  const float* x = (qs == 0 ? x0 : qs == 1 ? x1 : x2) + (size_t)b * C * N;
  const float* bias = (qs == 0 ? bias0 : qs == 1 ? bias1 : bias2);
  float* obase = out + (((size_t)(qs * 2 + b)) * 192 + (size_t)ks * 64) * (size_t)N;
  int ig = i0 + ln;
#pragma unroll
  for (int mc = 0; mc < 4; mc++) {
    const float* wr = wsel + (size_t)(mc * 16 + ln) * 64;  // A[m=ln][k=g*8+t]
    s16x8 wa0 = pack8s(wr + g * 8, 1.0f);
    s16x8 wa1 = pack8s(wr + 32 + g * 8, 1.0f);
    f32x4 d = (f32x4){0.f, 0.f, 0.f, 0.f};
    d = __builtin_amdgcn_mfma_f32_16x16x32_bf16(wa0, ob0, d, 0, 0, 0);
    d = __builtin_amdgcn_mfma_f32_16x16x32_bf16(wa1, ob1, d, 0, 0, 0);
#pragma unroll
    for (int r = 0; r < 4; r++) {
      int ch = mc * 16 + 4 * g + r;
      obase[(size_t)ch * N + ig] = d[r] + bias[ch] + x[(size_t)ch * N + ig];
    }
  }
}

// ---- fallback: R4-verified VALU anchor (fp32), used if ws too small -------
__global__ __launch_bounds__(256) void k_anchor(
    const float* q0, const float* q1, const float* q2,
    const float* k0, const float* k1, const float* k2,
    const float* v0, const float* v1, const float* v2,
    const float* x0, const float* x1, const float* x2,
    const float* w0, const float* w1, const float* w2,
    const float* b0, const float* b1, const float* b2,
    float* __restrict__ out) {
  __shared__ float orow[4][C];
  int slot = blockIdx.y;
  int b = slot / 9, rem = slot % 9, qs = rem / 3, ks = rem % 3;
  int tid = threadIdx.x, lane = tid & 63, wv = tid >> 6;
  int i = blockIdx.x * 4 + wv;
  const float* q = qs == 0 ? q0 : qs == 1 ? q1 : q2;
  const float* k = ks == 0 ? k0 : ks == 1 ? k1 : k2;
  const float* v = qs == 0 ? v0 : qs == 1 ? v1 : v2;
  const float* x = qs == 0 ? x0 : qs == 1 ? x1 : x2;
  const float* w = qs == 0 ? w0 : qs == 1 ? w1 : w2;
  const float* bb = qs == 0 ? b0 : qs == 1 ? b1 : b2;
  size_t qoff = (size_t)b * N * C + (size_t)i * C;
  size_t koff = (size_t)b * C * N;
  size_t voff = (size_t)b * C * N + (size_t)lane * N;
  float l_lane = 0.f, oacc = 0.f;
  for (int j0 = 0; j0 < N; j0 += 64) {
    float s = 0.f;
#pragma unroll
    for (int d = 0; d < C; d++)
      s += q[qoff + d] * k[koff + (size_t)d * N + j0 + lane];
    float e = exp2f(s * LOG2E);
    l_lane += e;
#pragma unroll
    for (int j = 0; j < 64; j += 4) {
      float4 v4 = *(const float4*)(v + voff + j0 + j);
      oacc += __shfl(e, j + 0) * v4.x + __shfl(e, j + 1) * v4.y +
              __shfl(e, j + 2) * v4.z + __shfl(e, j + 3) * v4.w;
    }
  }
  float l = l_lane;
#pragma unroll
  for (int off = 1; off < 64; off <<= 1) l += __shfl_xor(l, off);
  orow[wv][lane] = oacc / l;
  __syncthreads();
  float r = 0.f;
#pragma unroll
  for (int c = 0; c < C; c++) r += w[(size_t)lane * C + c] * orow[wv][c];
  out[(((size_t)(qs * 2 + b)) * 192 + (size_t)(ks * 64 + lane)) * (size_t)N + i] =
      r + bb[lane] + x[(size_t)b * C * N + (size_t)lane * N + i];
}

extern "C" void kernel_launch(void* const* d_in, const int* in_sizes, int n_in,
                              void* d_out, int out_size, void* d_ws, size_t ws_size,
                              hipStream_t stream) {
  (void)in_sizes; (void)n_in; (void)out_size;
  const float* poi_q   = (const float*)d_in[0];
  const float* poi_k   = (const float*)d_in[1];
  const float* poi_v   = (const float*)d_in[2];
  const float* x_poi   = (const float*)d_in[3];
  const float* point_q = (const float*)d_in[4];
  const float* point_k = (const float*)d_in[5];
  const float* point_v = (const float*)d_in[6];
  const float* x_point = (const float*)d_in[7];
  const float* pop_q   = (const float*)d_in[8];
  const float* pop_k   = (const float*)d_in[9];
  const float* pop_v   = (const float*)d_in[10];
  const float* x_pop   = (const float*)d_in[11];
  const float* w_poi   = (const float*)d_in[12];
  const float* b_poi   = (const float*)d_in[13];
  const float* w_point = (const float*)d_in[14];
  const float* b_point = (const float*)d_in[15];
  const float* w_pop   = (const float*)d_in[16];
  const float* b_pop   = (const float*)d_in[17];

  const size_t need = (size_t)12 * N * C * sizeof(unsigned short);  // 6 MB
  if (d_ws != nullptr && ws_size >= need) {
    unsigned short* KT = (unsigned short*)d_ws;
    unsigned short* Vb = KT + (size_t)6 * N * C;
    k_prep<<<1920, 256, 0, stream>>>(poi_k, point_k, pop_k,
                                     poi_v, point_v, pop_v, KT, Vb);
    k_flash<<<4608, 64, 0, stream>>>(poi_q, point_q, pop_q, KT, Vb,
                                     x_poi, x_point, x_pop,
                                     b_poi, b_point, b_pop,
                                     w_poi, w_point, w_pop, (float*)d_out);
  } else {
    k_anchor<<<dim3(1024, 18), 256, 0, stream>>>(
        poi_q, point_q, pop_q, poi_k, point_k, pop_k, poi_v, point_v, pop_v,
        x_poi, x_point, x_pop, w_poi, w_point, w_pop, b_poi, b_point, b_pop,
        (float*)d_out);
  }
}